// Round 21
// baseline (130.959 us; speedup 1.0000x reference)
//
#include <hip/hip_runtime.h>
#include <hip/hip_bf16.h>

#define L_SEQ    1024
#define IN_DIM   256
#define DIM_MSA  32
#define PAIR_DIM 64

typedef float f4 __attribute__((ext_vector_type(4)));
typedef short s8 __attribute__((ext_vector_type(8)));

__device__ __forceinline__ unsigned short f2bf(float f) {
    unsigned u = __float_as_uint(f);
    u = (u + 0x7FFFu + ((u >> 16) & 1u)) >> 16;   // RNE
    return (unsigned short)u;
}

// s[i][c] = b1[c] + sum_d seq[i][d] * W1[c][d]  (fp32 + bf16 copies)
__global__ void k_proj1(const float* __restrict__ seq, const float* __restrict__ W1,
                        const float* __restrict__ b1, float* __restrict__ s,
                        unsigned short* __restrict__ s_bf) {
    int t = blockIdx.x * blockDim.x + threadIdx.x;   // 1024*32 threads
    int i = t >> 5, c = t & 31;
    const float4* sq = (const float4*)(seq + i * IN_DIM);
    const float4* w  = (const float4*)(W1  + c * IN_DIM);
    float a0 = 0.f, a1 = 0.f, a2 = 0.f, a3 = 0.f;
#pragma unroll
    for (int d4 = 0; d4 < IN_DIM / 4; ++d4) {
        float4 x = sq[d4], y = w[d4];
        a0 += x.x * y.x;  a1 += x.y * y.y;
        a2 += x.z * y.z;  a3 += x.w * y.w;
    }
    float v = b1[c] + ((a0 + a1) + (a2 + a3));
    s[t]    = v;
    s_bf[t] = f2bf(v);
}

// tmp_bf[jp][d] = bf16( sum_c s[j][c] * W2[p][c*32+d] ), jp = j*64+p
__global__ void k_proj2(const float* __restrict__ s, const float* __restrict__ W2,
                        unsigned short* __restrict__ tmp_bf) {
    int t = blockIdx.x * blockDim.x + threadIdx.x;   // 1024*64*8 threads
    int q = t & 7, p = (t >> 3) & 63, j = t >> 9;
    const float4* w  = (const float4*)W2;            // idx = p*256 + c*8 + q
    const float*  sj = s + j * DIM_MSA;
    float4 acc = {0.f, 0.f, 0.f, 0.f};
#pragma unroll
    for (int c = 0; c < DIM_MSA; ++c) {
        float  sc = sj[c];
        float4 wv = w[p * 256 + c * 8 + q];
        acc.x += sc * wv.x;  acc.y += sc * wv.y;
        acc.z += sc * wv.z;  acc.w += sc * wv.w;
    }
    ushort4 o;
    o.x = f2bf(acc.x);  o.y = f2bf(acc.y);
    o.z = f2bf(acc.z);  o.w = f2bf(acc.w);
    ((ushort4*)tmp_bf)[t] = o;   // shorts 4t..4t+3 == [jp][d] row-major
}

// out[i][jp] = MFMA(tmp_bf, s_bf) + b2 + pair; LDS-transposed epilogue.
// R20 structure with the i-HALF SPLIT: two passes, each recomputes the 16
// MFMA tiles (matrix pipe is 1% utilized — free) and stores only 8 i-rows
// of C -> wave slab 8KB, block LDS 32KB -> 5 blocks/CU (was 2), WITHOUT
// narrowing the streams (4-wave, 256-jp, f4 1KB/instr) or adding VGPRs.
// Tests the phase-1 duty-cycle theory un-confounded.
__global__ __launch_bounds__(256) void k_outer_mfma9(
    const unsigned short* __restrict__ s_bf, const unsigned short* __restrict__ tmp_bf,
    const float* __restrict__ pair, const float* __restrict__ b2,
    float* __restrict__ out) {
    __shared__ float lds[4 * 8 * 256];           // 32 KB (4 waves x 8 KB)
    int tid = threadIdx.x;
    int w = tid >> 6, l = tid & 63;
    int n = l & 15, kg = l >> 4;
    int jb = blockIdx.x & 63;                    // jp-block fast axis
    int it = blockIdx.x >> 6;                    // i-tile

    // B-frag (N = i): s_bf[it*16 + n][kg*8 .. +7]
    s8 bs = *(const s8*)(s_bf + (size_t)(it * 16 + n) * DIM_MSA + kg * 8);

    int jp0 = jb * 1024 + w * 256;               // wave's jp range
    const unsigned short* ap = tmp_bf + (size_t)(jp0 + n) * DIM_MSA + kg * 8;
    float* myl = lds + w * 2048;                 // wave-private 8 KB

    f4 b4 = *(const f4*)(b2 + ((l * 4) & 63));

#pragma unroll
    for (int P = 0; P < 2; ++P) {
        // ---- phase 1: 16 MFMA tiles; keep C only for i-half P ----
#pragma unroll
        for (int t = 0; t < 16; ++t) {
            s8 at = *(const s8*)(ap + (size_t)t * 16 * DIM_MSA);  // L1/L2 hit
            f4 z = {0.f, 0.f, 0.f, 0.f};
            f4 c = __builtin_amdgcn_mfma_f32_16x16x32_bf16(at, bs, z, 0, 0, 0);
            // C: col = i = n, rows jp_loc = t*16 + kg*4 + (0..3) -> one b128
            if ((n >> 3) == P) {
                int col = (t * 16 + kg * 4) ^ ((n & 7) << 2); // swizzled
                *(f4*)(myl + (n & 7) * 256 + col) = c;
            }
        }
        // same-wave RAW through LDS (lgkmcnt); no barrier (wave-private slab)

        // ---- phase 2: stream 8 i-rows (f4 = 1KB/instr per wave) ----
        size_t rowbase = (size_t)(it * 16 + P * 8) * 65536 + (size_t)jp0 + l * 4;
        const float* pp = pair + rowbase;
        float*       op = out  + rowbase;
#pragma unroll
        for (int i = 0; i < 8; ++i) {
            int col = (l * 4) ^ (i << 2);                     // unswizzle
            f4 cc = *(const f4*)(myl + i * 256 + col);
            f4 pv = *(const f4*)(pp + (size_t)i * 65536);
            __builtin_nontemporal_store(cc + b4 + pv, (f4*)(op + (size_t)i * 65536));
        }
    }
}

extern "C" void kernel_launch(void* const* d_in, const int* in_sizes, int n_in,
                              void* d_out, int out_size, void* d_ws, size_t ws_size,
                              hipStream_t stream) {
    const float* seq  = (const float*)d_in[0];   // [1,1024,256]
    const float* pair = (const float*)d_in[1];   // [1,1024,1024,64]
    const float* W1   = (const float*)d_in[2];   // [32,256]
    const float* b1   = (const float*)d_in[3];   // [32]
    const float* W2   = (const float*)d_in[4];   // [64,1024]
    const float* b2   = (const float*)d_in[5];   // [64]
    float* out = (float*)d_out;

    float*          s_ws = (float*)d_ws;                     // 128 KB fp32
    unsigned short* sbf  = (unsigned short*)(s_ws + 32768);  // 64 KB bf16
    unsigned short* tbf  = sbf + 32768;                      // 4 MB bf16 [jp][d]

    k_proj1<<<(L_SEQ * DIM_MSA) / 256, 256, 0, stream>>>(seq, W1, b1, s_ws, sbf);
    k_proj2<<<(L_SEQ * PAIR_DIM * (DIM_MSA / 4)) / 256, 256, 0, stream>>>(s_ws, W2, tbf);
    k_outer_mfma9<<<64 * 64, 256, 0, stream>>>(sbf, tbf, pair, b2, out);
}

// Round 22
// 113.263 us; speedup vs baseline: 1.1562x; 1.1562x over previous
//
#include <hip/hip_runtime.h>
#include <hip/hip_bf16.h>

#define L_SEQ    1024
#define IN_DIM   256
#define DIM_MSA  32
#define PAIR_DIM 64

typedef float f4 __attribute__((ext_vector_type(4)));
typedef short s8 __attribute__((ext_vector_type(8)));

__device__ __forceinline__ unsigned short f2bf(float f) {
    unsigned u = __float_as_uint(f);
    u = (u + 0x7FFFu + ((u >> 16) & 1u)) >> 16;   // RNE
    return (unsigned short)u;
}

// s[i][c] = b1[c] + sum_d seq[i][d] * W1[c][d]  (fp32 + bf16 copies)
__global__ void k_proj1(const float* __restrict__ seq, const float* __restrict__ W1,
                        const float* __restrict__ b1, float* __restrict__ s,
                        unsigned short* __restrict__ s_bf) {
    int t = blockIdx.x * blockDim.x + threadIdx.x;   // 1024*32 threads
    int i = t >> 5, c = t & 31;
    const float4* sq = (const float4*)(seq + i * IN_DIM);
    const float4* w  = (const float4*)(W1  + c * IN_DIM);
    float a0 = 0.f, a1 = 0.f, a2 = 0.f, a3 = 0.f;
#pragma unroll
    for (int d4 = 0; d4 < IN_DIM / 4; ++d4) {
        float4 x = sq[d4], y = w[d4];
        a0 += x.x * y.x;  a1 += x.y * y.y;
        a2 += x.z * y.z;  a3 += x.w * y.w;
    }
    float v = b1[c] + ((a0 + a1) + (a2 + a3));
    s[t]    = v;
    s_bf[t] = f2bf(v);
}

// tmp_bf[jp][d] = bf16( sum_c s[j][c] * W2[p][c*32+d] ), jp = j*64+p
__global__ void k_proj2(const float* __restrict__ s, const float* __restrict__ W2,
                        unsigned short* __restrict__ tmp_bf) {
    int t = blockIdx.x * blockDim.x + threadIdx.x;   // 1024*64*8 threads
    int q = t & 7, p = (t >> 3) & 63, j = t >> 9;
    const float4* w  = (const float4*)W2;            // idx = p*256 + c*8 + q
    const float*  sj = s + j * DIM_MSA;
    float4 acc = {0.f, 0.f, 0.f, 0.f};
#pragma unroll
    for (int c = 0; c < DIM_MSA; ++c) {
        float  sc = sj[c];
        float4 wv = w[p * 256 + c * 8 + q];
        acc.x += sc * wv.x;  acc.y += sc * wv.y;
        acc.z += sc * wv.z;  acc.w += sc * wv.w;
    }
    ushort4 o;
    o.x = f2bf(acc.x);  o.y = f2bf(acc.y);
    o.z = f2bf(acc.z);  o.w = f2bf(acc.w);
    ((ushort4*)tmp_bf)[t] = o;   // shorts 4t..4t+3 == [jp][d] row-major
}

// out[i][jp] = MFMA(s_bf, tmp_bf) + b2 + pair; LDS-transposed epilogue.
// R14 EXACT (best measured: bench 112.2 us). Block = i-tile(16) x jp-block
// (1024). Wave w owns 256 jp + a private 16KB LDS slab. Phase 1: 16 MFMA
// tiles, C -> LDS [i_loc][jp_loc]. Phase 2: 16 i-rows, each pair load +
// LDS read + nt store at 1KB/instr per wave (4KB/block contiguous).
// No barriers (wave-private slab, same-wave RAW via lgkmcnt).
__global__ __launch_bounds__(256) void k_outer_mfma2(
    const unsigned short* __restrict__ s_bf, const unsigned short* __restrict__ tmp_bf,
    const float* __restrict__ pair, const float* __restrict__ b2,
    float* __restrict__ out) {
    __shared__ float lds[4 * 16 * 256];          // 64 KB
    int tid = threadIdx.x;
    int w = tid >> 6, l = tid & 63;
    int n = l & 15, kg = l >> 4;
    int jb = blockIdx.x & 63;                    // jp-block fast axis
    int it = blockIdx.x >> 6;                    // i-tile

    // A-frag: s_bf[it*16 + n][kg*8 .. +7]
    s8 a = *(const s8*)(s_bf + (size_t)(it * 16 + n) * DIM_MSA + kg * 8);

    int jp0 = jb * 1024 + w * 256;               // wave's jp range
    const unsigned short* bp = tmp_bf + (size_t)(jp0 + n) * DIM_MSA + kg * 8;
    float* myl = lds + w * 4096;                 // wave-private 16 KB

    // ---- phase 1: 16 MFMA tiles -> LDS [16 i][256 jp] ----
#pragma unroll
    for (int t = 0; t < 16; ++t) {
        s8 b = *(const s8*)(bp + (size_t)t * 16 * DIM_MSA);  // 1KB/wave, L2
        f4 z = {0.f, 0.f, 0.f, 0.f};
        f4 c = __builtin_amdgcn_mfma_f32_16x16x32_bf16(a, b, z, 0, 0, 0);
        // C: reg r -> i_loc = kg*4 + r, jp_loc = t*16 + n
        float* dst = myl + (kg * 4) * 256 + t * 16 + n;
        dst[0]   = c.x;
        dst[256] = c.y;
        dst[512] = c.z;
        dst[768] = c.w;
    }
    // same-wave RAW through LDS: compiler inserts lgkmcnt wait; no barrier.

    // ---- phase 2: stream 16 i-rows (f4 = 1KB/instr per wave) ----
    f4 b4 = *(const f4*)(b2 + ((l * 4) & 63));
    size_t rowbase = (size_t)(it * 16) * 65536 + (size_t)jp0 + l * 4;
    const float* pp = pair + rowbase;
    float*       op = out  + rowbase;

#pragma unroll 8
    for (int i = 0; i < 16; ++i) {
        f4 cc = *(const f4*)(myl + i * 256 + l * 4);
        f4 pv = *(const f4*)(pp + (size_t)i * 65536);
        __builtin_nontemporal_store(cc + b4 + pv, (f4*)(op + (size_t)i * 65536));
    }
}

extern "C" void kernel_launch(void* const* d_in, const int* in_sizes, int n_in,
                              void* d_out, int out_size, void* d_ws, size_t ws_size,
                              hipStream_t stream) {
    const float* seq  = (const float*)d_in[0];   // [1,1024,256]
    const float* pair = (const float*)d_in[1];   // [1,1024,1024,64]
    const float* W1   = (const float*)d_in[2];   // [32,256]
    const float* b1   = (const float*)d_in[3];   // [32]
    const float* W2   = (const float*)d_in[4];   // [64,1024]
    const float* b2   = (const float*)d_in[5];   // [64]
    float* out = (float*)d_out;

    float*          s_ws = (float*)d_ws;                     // 128 KB fp32
    unsigned short* sbf  = (unsigned short*)(s_ws + 32768);  // 64 KB bf16
    unsigned short* tbf  = sbf + 32768;                      // 4 MB bf16 [jp][d]

    k_proj1<<<(L_SEQ * DIM_MSA) / 256, 256, 0, stream>>>(seq, W1, b1, s_ws, sbf);
    k_proj2<<<(L_SEQ * PAIR_DIM * (DIM_MSA / 4)) / 256, 256, 0, stream>>>(s_ws, W2, tbf);
    k_outer_mfma2<<<64 * 64, 256, 0, stream>>>(sbf, tbf, pair, b2, out);
}